// Round 4
// baseline (127.550 us; speedup 1.0000x reference)
//
#include <hip/hip_runtime.h>
#include <hip/hip_cooperative_groups.h>

namespace cg = cooperative_groups;

#define BLK 256
#define ITILE 256            // i's per block (scalar-looped)
#define KJ 2                 // j's per thread, register-resident
#define JTILE (BLK * KJ)     // 512
#define GX 32                // 8192 / ITILE
#define GY 16                // 8192 / JTILE
#define NSLOTS (GX * GY)     // 512

__global__ __launch_bounds__(BLK) void svm_fused(
    const float* __restrict__ pred,
    const float2* __restrict__ tg,
    float* __restrict__ ws_rank,
    float* __restrict__ ws_reg,
    unsigned int* __restrict__ ws_cnt,
    float* __restrict__ out,
    int n) {
  const int tid = threadIdx.x;
  const int i0 = blockIdx.x * ITILE;
  const int j0 = blockIdx.y * JTILE;

  // Per-lane j data: loaded once, lives in VGPRs.
  float pj[KJ], tj[KJ];
  #pragma unroll
  for (int k = 0; k < KJ; ++k) {
    pj[k] = pred[j0 + tid + k * BLK];
    tj[k] = tg[j0 + tid + k * BLK].x;
  }

  float rank = 0.0f;
  unsigned int cnt = 0u;

  // i is wave-uniform: loads scalarize (s_load); event check is a
  // uniform scalar branch that skips ~half the i's entirely.
  for (int ib = 0; ib < ITILE; ib += 8) {
    float pi[8], ti[8], ei[8];
    #pragma unroll
    for (int u = 0; u < 8; ++u) {
      pi[u] = pred[i0 + ib + u];
      float2 te = tg[i0 + ib + u];
      ti[u] = te.x;
      ei[u] = te.y;
    }
    #pragma unroll
    for (int u = 0; u < 8; ++u) {
      if (ei[u] == 1.0f) {
        const float pi1 = pi[u] + 1.0f;
        #pragma unroll
        for (int k = 0; k < KJ; ++k) {
          const float h = fmaxf(pi1 - pj[k], 0.0f);
          const bool m = tj[k] > ti[u];
          const float hm = m ? h : 0.0f;
          rank = fmaf(hm, hm, rank);
          cnt += m ? 1u : 0u;
        }
      }
    }
  }

  // Regression term: per-lane i, counted once (y==0 slice only).
  float reg = 0.0f;
  if (blockIdx.y == 0) {
    const int i = i0 + tid;
    const float p = pred[i];
    const float2 te = tg[i];
    float d = p - te.x;
    if (te.y == 0.0f) d = fmaxf(d, 0.0f);
    reg = d * d;
  }

  // 64-lane shuffle reduction
  #pragma unroll
  for (int off = 32; off > 0; off >>= 1) {
    rank += __shfl_down(rank, off);
    reg  += __shfl_down(reg, off);
    cnt  += __shfl_down(cnt, off);
  }

  __shared__ float sr[BLK / 64];
  __shared__ float sg[BLK / 64];
  __shared__ unsigned int sc[BLK / 64];
  const int wave = tid >> 6;
  const int lane = tid & 63;
  if (lane == 0) { sr[wave] = rank; sg[wave] = reg; sc[wave] = cnt; }
  __syncthreads();

  if (tid == 0) {
    float r = 0.f, g = 0.f;
    unsigned int c = 0u;
    #pragma unroll
    for (int w = 0; w < BLK / 64; ++w) { r += sr[w]; g += sg[w]; c += sc[w]; }
    const int slot = blockIdx.y * GX + blockIdx.x;
    ws_rank[slot] = r;
    ws_reg[slot]  = g;
    ws_cnt[slot]  = c;
  }

  // ---- grid-wide barrier, then block 0 finalizes ----
  cg::this_grid().sync();

  if (blockIdx.x == 0 && blockIdx.y == 0) {
    double r = 0.0, g = 0.0;
    unsigned long long c = 0ull;
    for (int s = tid; s < NSLOTS; s += BLK) {
      r += (double)ws_rank[s];
      g += (double)ws_reg[s];
      c += (unsigned long long)ws_cnt[s];
    }
    #pragma unroll
    for (int off = 32; off > 0; off >>= 1) {
      r += __shfl_down(r, off);
      g += __shfl_down(g, off);
      c += __shfl_down(c, off);
    }
    __shared__ double dr[BLK / 64];
    __shared__ double dg[BLK / 64];
    __shared__ unsigned long long dc[BLK / 64];
    if (lane == 0) { dr[wave] = r; dg[wave] = g; dc[wave] = c; }
    __syncthreads();
    if (tid == 0) {
      r = dr[0] + dr[1] + dr[2] + dr[3];
      g = dg[0] + dg[1] + dg[2] + dg[3];
      c = dc[0] + dc[1] + dc[2] + dc[3];
      const double cd = (double)(c > 0ull ? c : 1ull);
      out[0] = (float)(0.5 * r / cd + 0.5 * g / (double)n);
    }
  }
}

extern "C" void kernel_launch(void* const* d_in, const int* in_sizes, int n_in,
                              void* d_out, int out_size, void* d_ws, size_t ws_size,
                              hipStream_t stream) {
  const float* pred = (const float*)d_in[0];
  const float2* tg = (const float2*)d_in[1];
  float* out = (float*)d_out;
  int n = in_sizes[0];  // 8192

  float* ws_rank = (float*)d_ws;
  float* ws_reg  = (float*)((char*)d_ws + NSLOTS * sizeof(float));
  unsigned int* ws_cnt = (unsigned int*)((char*)d_ws + 2 * NSLOTS * sizeof(float));

  void* args[] = {(void*)&pred, (void*)&tg, (void*)&ws_rank, (void*)&ws_reg,
                  (void*)&ws_cnt, (void*)&out, (void*)&n};
  hipLaunchCooperativeKernel((const void*)svm_fused, dim3(GX, GY), dim3(BLK),
                             args, 0, stream);
}

// Round 5
// 72.805 us; speedup vs baseline: 1.7519x; 1.7519x over previous
//
#include <hip/hip_runtime.h>

#define BLK 256
#define ITILE 256            // i's per block (wave-uniform scalar loop; == BLK for reg term)
#define GX 32                // 8192 / ITILE
#define GY 32                // 8192 / BLK   (1 j per thread, register-resident)
#define NSLOTS (GX * GY)     // 1024

__global__ __launch_bounds__(BLK) void svm_partial(
    const float* __restrict__ pred,
    const float2* __restrict__ tg,
    float* __restrict__ ws_rank,
    float* __restrict__ ws_reg,
    unsigned int* __restrict__ ws_cnt) {
  const int tid = threadIdx.x;
  const int i0 = blockIdx.x * ITILE;
  const int j0 = blockIdx.y * BLK;

  // Per-lane j data: loaded once, lives in VGPRs.
  const float pj = pred[j0 + tid];
  const float tj = tg[j0 + tid].x;

  float rank = 0.0f;
  unsigned long long cnt = 0ull;   // wave-uniform (ballot/popcount path)

  // i is wave-uniform: loads scalarize (s_load); event check is a
  // uniform scalar branch skipping ~half the i's.
  for (int ib = 0; ib < ITILE; ib += 8) {
    float pi[8], ti[8], ei[8];
    #pragma unroll
    for (int u = 0; u < 8; ++u) {
      pi[u] = pred[i0 + ib + u];
      float2 te = tg[i0 + ib + u];
      ti[u] = te.x;
      ei[u] = te.y;
    }
    #pragma unroll
    for (int u = 0; u < 8; ++u) {
      if (ei[u] == 1.0f) {
        const float pi1 = pi[u] + 1.0f;
        const bool m = tj > ti[u];
        cnt += __popcll(__ballot(m));          // scalar pipe: s_bcnt1 + s_add
        float h = m ? (pi1 - pj) : 0.0f;       // sub + cndmask
        h = fmaxf(h, 0.0f);
        rank = fmaf(h, h, rank);
      }
    }
  }

  // Regression term: per-lane i, counted once (y==0 slice only).
  float reg = 0.0f;
  if (blockIdx.y == 0) {
    const int i = i0 + tid;
    const float p = pred[i];
    const float2 te = tg[i];
    float d = p - te.x;
    if (te.y == 0.0f) d = fmaxf(d, 0.0f);
    reg = d * d;
  }

  // 64-lane shuffle reduction (rank/reg only; cnt is wave-uniform)
  #pragma unroll
  for (int off = 32; off > 0; off >>= 1) {
    rank += __shfl_down(rank, off);
    reg  += __shfl_down(reg, off);
  }

  __shared__ float sr[BLK / 64];
  __shared__ float sg[BLK / 64];
  __shared__ unsigned long long sc[BLK / 64];
  const int wave = tid >> 6;
  const int lane = tid & 63;
  if (lane == 0) { sr[wave] = rank; sg[wave] = reg; sc[wave] = cnt; }
  __syncthreads();

  if (tid == 0) {
    float r = 0.f, g = 0.f;
    unsigned long long c = 0ull;
    #pragma unroll
    for (int w = 0; w < BLK / 64; ++w) { r += sr[w]; g += sg[w]; c += sc[w]; }
    const int slot = blockIdx.y * GX + blockIdx.x;
    ws_rank[slot] = r;
    ws_reg[slot]  = g;
    ws_cnt[slot]  = (unsigned int)c;   // <= 65536 pairs/block, fits
  }
}

__global__ __launch_bounds__(BLK) void svm_finalize(
    const float* __restrict__ ws_rank,
    const float* __restrict__ ws_reg,
    const unsigned int* __restrict__ ws_cnt,
    float* __restrict__ out, int n) {
  const int tid = threadIdx.x;
  double r = 0.0, g = 0.0;
  unsigned long long c = 0ull;
  for (int s = tid; s < NSLOTS; s += BLK) {
    r += (double)ws_rank[s];
    g += (double)ws_reg[s];
    c += (unsigned long long)ws_cnt[s];
  }
  #pragma unroll
  for (int off = 32; off > 0; off >>= 1) {
    r += __shfl_down(r, off);
    g += __shfl_down(g, off);
    c += __shfl_down(c, off);
  }
  __shared__ double dr[BLK / 64];
  __shared__ double dg[BLK / 64];
  __shared__ unsigned long long dc[BLK / 64];
  const int wave = tid >> 6;
  const int lane = tid & 63;
  if (lane == 0) { dr[wave] = r; dg[wave] = g; dc[wave] = c; }
  __syncthreads();
  if (tid == 0) {
    r = dr[0] + dr[1] + dr[2] + dr[3];
    g = dg[0] + dg[1] + dg[2] + dg[3];
    c = dc[0] + dc[1] + dc[2] + dc[3];
    const double cd = (double)(c > 0ull ? c : 1ull);
    out[0] = (float)(0.5 * r / cd + 0.5 * g / (double)n);
  }
}

extern "C" void kernel_launch(void* const* d_in, const int* in_sizes, int n_in,
                              void* d_out, int out_size, void* d_ws, size_t ws_size,
                              hipStream_t stream) {
  const float* pred = (const float*)d_in[0];
  const float2* tg = (const float2*)d_in[1];
  float* out = (float*)d_out;
  const int n = in_sizes[0];  // 8192

  float* ws_rank = (float*)d_ws;
  float* ws_reg  = (float*)((char*)d_ws + NSLOTS * sizeof(float));
  unsigned int* ws_cnt = (unsigned int*)((char*)d_ws + 2 * NSLOTS * sizeof(float));

  dim3 grid(GX, GY);
  svm_partial<<<grid, BLK, 0, stream>>>(pred, tg, ws_rank, ws_reg, ws_cnt);
  svm_finalize<<<1, BLK, 0, stream>>>(ws_rank, ws_reg, ws_cnt, out, n);
}